// Round 3
// baseline (68.520 us; speedup 1.0000x reference)
//
#include <hip/hip_runtime.h>
#include <stdint.h>

#define NROWS 8192
#define FDIM  256   // K (feature dim)
#define DDIM  64    // N (out dim)

typedef __attribute__((ext_vector_type(8))) short short8;   // 8 bf16 = 4 VGPR (MFMA A/B frag)
typedef __attribute__((ext_vector_type(4))) float floatx4;  // MFMA C/D frag

// d_ws layout: [0, 32768) bytes = 2048 B-frags (8 ksteps x 4 ntiles x 64 lanes) x 16 B,
//              [32768, 33024) = 64-float bias colsum.
// Frag index f = ks*256 + nt*64 + lane; frag holds W[ks*32 + (lane>>4)*8 + k][nt*16 + (lane&15)],
// k=0..7 packed as bf16 pairs — exactly the B-operand layout validated in R2 (absmax 9.77e-4).

// Pack two fp32 -> bf16x2, round-to-nearest-even (inputs finite; no NaN path needed).
__device__ inline unsigned int pack2_bf16(float a, float b) {
    unsigned int ua = __float_as_uint(a);
    unsigned int ub = __float_as_uint(b);
    ua += 0x7fffu + ((ua >> 16) & 1u);
    ub += 0x7fffu + ((ub >> 16) & 1u);
    return (ua >> 16) | (ub & 0xffff0000u);
}

// ---- Kernel 1: pack W -> frag-ready bf16 in d_ws; bias colsum -> d_ws. ----
// Blocks 0..15: 128 threads x 1 frag each (16*128 = 2048 frags).
// Block 16: threads 0..63 each sum one bias column (256 coalesced-row dword loads).
__global__ __launch_bounds__(128)
void nanembed_pack(const float* __restrict__ W,
                   const float* __restrict__ b,
                   void* __restrict__ ws)
{
    const int bid = blockIdx.x;
    const int tid = threadIdx.x;
    if (bid < 16) {
        const int f  = bid * 128 + tid;      // 0..2047
        const int ks = f >> 8;
        const int nt = (f >> 6) & 3;
        const int fl = f & 63;
        const int fq = fl >> 4;
        const int c  = nt * 16 + (fl & 15);
        const float* wp = W + (size_t)(ks * 32 + fq * 8) * DDIM + c;
        union { short8 s; unsigned int u[4]; } fr;
        fr.u[0] = pack2_bf16(wp[0 * DDIM], wp[1 * DDIM]);
        fr.u[1] = pack2_bf16(wp[2 * DDIM], wp[3 * DDIM]);
        fr.u[2] = pack2_bf16(wp[4 * DDIM], wp[5 * DDIM]);
        fr.u[3] = pack2_bf16(wp[6 * DDIM], wp[7 * DDIM]);
        reinterpret_cast<short8*>(ws)[f] = fr.s;
    } else if (tid < DDIM) {
        float s = 0.f;
        #pragma unroll 16
        for (int f = 0; f < FDIM; ++f)
            s += b[(size_t)f * DDIM + tid];
        reinterpret_cast<float*>(ws)[8192 + tid] = s;   // byte offset 32768
    }
}

// ---- Kernel 2: pure streaming MFMA, no LDS, no barriers. ----
// 512 blocks x 64 threads; wave = one 16-row x 64-col tile, K=256 = 8 ksteps x 4 ntiles.
// Layouts (empirically validated in R2):
//   A[m=lane&15][k=(lane>>4)*8+j], B-frags preloaded, D col=lane&15 row=(lane>>4)*4+reg.
__global__ __launch_bounds__(64)
void nanembed_mfma2(const float* __restrict__ x,
                    const void* __restrict__ ws,
                    float* __restrict__ out)
{
    const int lane = threadIdx.x;
    const int q    = lane >> 4;
    const int n    = lane & 15;
    const int r0   = blockIdx.x * 16;

    // x loads first: 16 independent dwordx4, one HBM latency for the whole tile.
    const float4* xp = reinterpret_cast<const float4*>(x + (size_t)(r0 + n) * FDIM + q * 8);
    float4 xv[16];
    #pragma unroll
    for (int ks = 0; ks < 8; ++ks) {
        xv[2 * ks]     = xp[ks * 8];      // k = ks*32 + q*8 + 0..3
        xv[2 * ks + 1] = xp[ks * 8 + 1];  // k = ks*32 + q*8 + 4..7
    }

    const short8* bf   = reinterpret_cast<const short8*>(ws);
    const float*  bias = reinterpret_cast<const float*>(ws) + 8192;
    float bsv[4];
    #pragma unroll
    for (int nt = 0; nt < 4; ++nt) bsv[nt] = bias[nt * 16 + n];

    floatx4 acc[4] = {{0.f, 0.f, 0.f, 0.f}, {0.f, 0.f, 0.f, 0.f},
                      {0.f, 0.f, 0.f, 0.f}, {0.f, 0.f, 0.f, 0.f}};
    #pragma unroll
    for (int ks = 0; ks < 8; ++ks) {
        union { short8 s; unsigned int u[4]; } fa;
        float4 v0 = xv[2 * ks], v1 = xv[2 * ks + 1];
        fa.u[0] = pack2_bf16(v0.x, v0.y);
        fa.u[1] = pack2_bf16(v0.z, v0.w);
        fa.u[2] = pack2_bf16(v1.x, v1.y);
        fa.u[3] = pack2_bf16(v1.z, v1.w);
        #pragma unroll
        for (int nt = 0; nt < 4; ++nt) {
            short8 fb = bf[ks * 256 + nt * 64 + lane];   // coalesced dwordx4, L2/L3-hot
            acc[nt] = __builtin_amdgcn_mfma_f32_16x16x32_bf16(fa.s, fb, acc[nt], 0, 0, 0);
        }
    }

    // Epilogue: bias + 1/256 scale; 16 dword stores (64B-coalesced per 16-lane group).
    #pragma unroll
    for (int nt = 0; nt < 4; ++nt) {
        const int c = nt * 16 + n;
        #pragma unroll
        for (int reg = 0; reg < 4; ++reg) {
            const int r = r0 + q * 4 + reg;
            out[(size_t)r * DDIM + c] = (acc[nt][reg] + bsv[nt]) * (1.0f / 256.0f);
        }
    }
}

extern "C" void kernel_launch(void* const* d_in, const int* in_sizes, int n_in,
                              void* d_out, int out_size, void* d_ws, size_t ws_size,
                              hipStream_t stream) {
    const float* x = (const float*)d_in[0];   // [8192, 256]
    const float* W = (const float*)d_in[1];   // [256, 64]
    const float* b = (const float*)d_in[2];   // [256, 64]
    float* out = (float*)d_out;               // [8192, 64]

    nanembed_pack<<<dim3(17), 128, 0, stream>>>(W, b, d_ws);
    nanembed_mfma2<<<dim3(NROWS / 16), 64, 0, stream>>>(x, d_ws, out);
}

// Round 4
// 65.792 us; speedup vs baseline: 1.0415x; 1.0415x over previous
//
#include <hip/hip_runtime.h>
#include <stdint.h>

#define NROWS 8192
#define FDIM  256   // K (feature dim)
#define DDIM  64    // N (out dim)

typedef __attribute__((ext_vector_type(8))) short short8;   // 8 bf16 = 4 VGPR (MFMA A/B frag)
typedef __attribute__((ext_vector_type(4))) float floatx4;  // MFMA C/D frag

// Single fused dispatch (R2 structure — best measured: 65.6 us vs 68.5 for the
// split-dispatch variant; the inter-kernel dependency edge cost more than the
// per-block W repack it saved, since the repack hides under x's HBM latency).

// Pack two fp32 -> bf16x2, round-to-nearest-even (inputs finite; no NaN path needed).
__device__ inline unsigned int pack2_bf16(float a, float b) {
    unsigned int ua = __float_as_uint(a);
    unsigned int ub = __float_as_uint(b);
    ua += 0x7fffu + ((ua >> 16) & 1u);
    ub += 0x7fffu + ((ub >> 16) & 1u);
    return (ua >> 16) | (ub & 0xffff0000u);
}

// Block: 128 threads = 2 waves; each wave computes 16 rows x 64 cols via
// mfma_f32_16x16x32_bf16 (4 n-tiles x 8 k-steps = 32 MFMAs). Grid: 256 blocks
// (8192/32 rows), 1 block/CU — spreads the 8 MB x stream over all 256 CUs
// (per-CU L1 BW would throttle fewer, fatter blocks).
//
// Layouts (empirically validated R2/R3, absmax 9.77e-4):
//   A[m=lane&15][k=(lane>>4)*8+j]   (x rows, straight from global, packed in regs)
//   B[k=(lane>>4)*8+j][n=lane&15]   (W, pre-packed frag-ready in LDS -> 1 ds_read_b128/MFMA)
//   D col=lane&15, row=(lane>>4)*4+reg
__global__ __launch_bounds__(128)
void nanembed_mfma(const float* __restrict__ x,
                   const float* __restrict__ W,
                   const float* __restrict__ b,
                   float* __restrict__ out)
{
    // 2048 B-frags (8 ksteps x 4 ntiles x 64 lanes) x 16B = 32 KB
    __shared__ __align__(16) unsigned int bfrag_lds[2048 * 4];
    __shared__ float4 bias_part[8][16];   // 2 KB: partial colsum(b), 8 f-chunks x 64 cols

    const int tid  = threadIdx.x;     // 0..127
    const int lane = tid & 63;
    const int w    = tid >> 6;        // wave id 0/1
    const int q    = lane >> 4;       // quad 0..3
    const int n    = lane & 15;
    const int r0   = blockIdx.x * 32;

    // ---- 1) x loads first: 16 independent dwordx4/lane issued before any other
    //         work, so the HBM latency is covered by the W/bias staging below.
    const int row = r0 + w * 16 + n;
    const float4* xp = reinterpret_cast<const float4*>(x + (size_t)row * FDIM + q * 8);
    float4 xv[16];
    #pragma unroll
    for (int ks = 0; ks < 8; ++ks) {
        xv[2 * ks]     = xp[ks * 8];      // k = ks*32 + q*8 + 0..3
        xv[2 * ks + 1] = xp[ks * 8 + 1];  // k = ks*32 + q*8 + 4..7
    }

    // ---- 2) Stage W into frag-ready LDS layout: frag f = ks*256 + nt*64 + lane.
    //         16 frags/thread; each frag = 8 strided L2-hot W loads (64 KB/block),
    //         packed to bf16x8, one ds_write_b128.
    #pragma unroll
    for (int i = 0; i < 16; ++i) {
        int f  = tid + i * 128;          // 0..2047
        int ks = f >> 8;
        int nt = (f >> 6) & 3;
        int fl = f & 63;
        int fq = fl >> 4;
        int c  = nt * 16 + (fl & 15);
        const float* wp = W + (size_t)(ks * 32 + fq * 8) * DDIM + c;
        union { short8 s; unsigned int u[4]; } fr;
        fr.u[0] = pack2_bf16(wp[0 * DDIM], wp[1 * DDIM]);
        fr.u[1] = pack2_bf16(wp[2 * DDIM], wp[3 * DDIM]);
        fr.u[2] = pack2_bf16(wp[4 * DDIM], wp[5 * DDIM]);
        fr.u[3] = pack2_bf16(wp[6 * DDIM], wp[7 * DDIM]);
        reinterpret_cast<short8*>(bfrag_lds)[f] = fr.s;
    }

    // ---- 3) Bias partial colsums: thread (h=tid>>4, c4=tid&15) sums 32 f-rows
    //         of float4 column group c4. Coalesced, L2-hot.
    {
        const int c4 = tid & 15;
        const int h  = tid >> 4;         // 0..7
        const float4* bp = reinterpret_cast<const float4*>(b) + c4;
        float4 s = make_float4(0.f, 0.f, 0.f, 0.f);
        #pragma unroll 8
        for (int f = h * 32; f < h * 32 + 32; ++f) {
            float4 v = bp[(size_t)f * 16];
            s.x += v.x; s.y += v.y; s.z += v.z; s.w += v.w;
        }
        bias_part[h][c4] = s;
    }

    __syncthreads();

    // ---- 4) MFMA K-loop: pack A-frag from regs (x has landed by now),
    //         one ds_read_b128 per B-frag (conflict-free: lane-indexed).
    floatx4 acc[4] = {{0.f, 0.f, 0.f, 0.f}, {0.f, 0.f, 0.f, 0.f},
                      {0.f, 0.f, 0.f, 0.f}, {0.f, 0.f, 0.f, 0.f}};
    #pragma unroll
    for (int ks = 0; ks < 8; ++ks) {
        union { short8 s; unsigned int u[4]; } fa;
        float4 v0 = xv[2 * ks], v1 = xv[2 * ks + 1];
        fa.u[0] = pack2_bf16(v0.x, v0.y);
        fa.u[1] = pack2_bf16(v0.z, v0.w);
        fa.u[2] = pack2_bf16(v1.x, v1.y);
        fa.u[3] = pack2_bf16(v1.z, v1.w);
        #pragma unroll
        for (int nt = 0; nt < 4; ++nt) {
            short8 fb = reinterpret_cast<const short8*>(bfrag_lds)[ks * 256 + nt * 64 + lane];
            acc[nt] = __builtin_amdgcn_mfma_f32_16x16x32_bf16(fa.s, fb, acc[nt], 0, 0, 0);
        }
    }

    // ---- 5) Epilogue: fold bias (exact fp32 colsum) + 1/256 scale; 16 dword
    //         stores, 64B-coalesced per 16-lane group.
    #pragma unroll
    for (int nt = 0; nt < 4; ++nt) {
        const int c = nt * 16 + n;
        float bs = 0.f;
        #pragma unroll
        for (int h = 0; h < 8; ++h)
            bs += reinterpret_cast<const float*>(&bias_part[h][0])[c];  // broadcast reads
        #pragma unroll
        for (int reg = 0; reg < 4; ++reg) {
            const int r = r0 + w * 16 + q * 4 + reg;
            out[(size_t)r * DDIM + c] = (acc[nt][reg] + bs) * (1.0f / 256.0f);
        }
    }
}

extern "C" void kernel_launch(void* const* d_in, const int* in_sizes, int n_in,
                              void* d_out, int out_size, void* d_ws, size_t ws_size,
                              hipStream_t stream) {
    const float* x = (const float*)d_in[0];   // [8192, 256]
    const float* W = (const float*)d_in[1];   // [256, 64]
    const float* b = (const float*)d_in[2];   // [256, 64]
    float* out = (float*)d_out;               // [8192, 64]

    nanembed_mfma<<<dim3(NROWS / 32), 128, 0, stream>>>(x, W, b, out);
}